// Round 1
// baseline (8128.284 us; speedup 1.0000x reference)
//
#include <hip/hip_runtime.h>
#include <math.h>

// Problem constants
constexpr int NB  = 1024;   // batch
constexpr int NL  = 96;     // seq len L
constexpr int ND  = 128;    // D
constexpr int NHS = 512;    // hidden
constexpr int NT  = 24;     // timesteps
constexpr int NN  = 128;    // attention dim N
constexpr int NG4 = 4 * NHS; // 2048

// ---------------------------------------------------------------- init state
__global__ __launch_bounds__(256) void k_init(const float* __restrict__ emb,
                                              const float* __restrict__ y0,
                                              float* __restrict__ c,
                                              float* __restrict__ h,
                                              float* __restrict__ y) {
    int idx = blockIdx.x * blockDim.x + threadIdx.x;
    if (idx < NB * NHS) {
        int b = idx / NHS, s = idx - b * NHS;
        h[idx] = emb[b * 2 * NHS + s];
        c[idx] = emb[b * 2 * NHS + NHS + s];
    }
    if (idx < NB) y[idx] = y0[idx];
}

// ---------------------------------------------------------------- cUa = c @ Ua[:,t,:]
// grid: NB/8 blocks, 256 threads. LDS-stage 8 c-rows, split K across 2 half-blocks.
__global__ __launch_bounds__(256) void k_cua(const float* __restrict__ c,
                                             const float* __restrict__ Ua,
                                             float* __restrict__ cua, int t) {
    __shared__ float cs[8 * NHS];       // 16 KB
    __shared__ float red[8][NN];        // 4 KB
    int tid = threadIdx.x;
    int b0 = blockIdx.x * 8;
    for (int i = tid; i < 8 * NHS; i += 256) cs[i] = c[b0 * NHS + i];
    __syncthreads();
    int kg = tid >> 7;          // 0/1: K half
    int n  = tid & 127;
    float acc[8] = {0, 0, 0, 0, 0, 0, 0, 0};
    int k0 = kg * 256;
    for (int k = k0; k < k0 + 256; ++k) {
        float ua = Ua[k * (NT * NN) + t * NN + n];
#pragma unroll
        for (int r = 0; r < 8; ++r) acc[r] += cs[r * NHS + k] * ua;
    }
    if (kg == 1) {
#pragma unroll
        for (int r = 0; r < 8; ++r) red[r][n] = acc[r];
    }
    __syncthreads();
    if (kg == 0) {
#pragma unroll
        for (int r = 0; r < 8; ++r) cua[(b0 + r) * NN + n] = acc[r] + red[r][n];
    }
}

// ---------------------------------------------------------------- attention (one block per b)
// score[l] = scale * sum_n va[n]*tanh( H[b,l,:]·Wa[:,t,n] + cua[b,n] + ba[t,n] )
// beta = softmax(score); h_t[b,:] = sum_l beta[l]*H[b,l,:]
__global__ __launch_bounds__(256, 2) void k_attn(const float* __restrict__ Hg,
                                                 const float* __restrict__ Wa,
                                                 const float* __restrict__ Va,
                                                 const float* __restrict__ ba,
                                                 const float* __restrict__ cua,
                                                 float* __restrict__ ht, int t) {
    // Ws[d/4][n][d%4]: lane n reads one contiguous float4 per 4-d chunk
    __shared__ float Ws[32][NN][4];     // 64 KB
    __shared__ float sc[NL];
    __shared__ float red[2][8][2];
    int tid = threadIdx.x;
    int b = blockIdx.x;
    const float* __restrict__ Hb = Hg + (size_t)b * (NL * ND);

    for (int i = tid; i < (ND * NN) / 4; i += 256) {
        int d = i >> 5, n4 = (i & 31) << 2;
        const float4 v = *(const float4*)&Wa[d * (NT * NN) + t * NN + n4];
        Ws[d >> 2][n4 + 0][d & 3] = v.x;
        Ws[d >> 2][n4 + 1][d & 3] = v.y;
        Ws[d >> 2][n4 + 2][d & 3] = v.z;
        Ws[d >> 2][n4 + 3][d & 3] = v.w;
    }
    __syncthreads();

    int grp = tid >> 7;             // 0/1 -> l in [grp*48, grp*48+48)
    int n   = tid & 127;
    int wig = (tid >> 6) & 1;       // wave within group
    float cb = cua[b * NN + n] + ba[t * NN + n];
    float va = Va[n * NT + t];      // Va is (N,T,1)
    const float scale = 0.044194173824159216f;  // 1/sqrt(512)

    for (int it = 0; it < 6; ++it) {
        int l0 = grp * 48 + it * 8;
        float acc[8] = {0, 0, 0, 0, 0, 0, 0, 0};
        const float* __restrict__ hrow = Hb + l0 * ND;
        for (int d0 = 0; d0 < 32; ++d0) {
            float4 w = *(const float4*)&Ws[d0][n][0];
#pragma unroll
            for (int j = 0; j < 8; ++j) {
                float4 hv = *(const float4*)&hrow[j * ND + d0 * 4];
                acc[j] += hv.x * w.x + hv.y * w.y + hv.z * w.z + hv.w * w.w;
            }
        }
#pragma unroll
        for (int j = 0; j < 8; ++j) {
            float v = va * tanhf(acc[j] + cb);
#pragma unroll
            for (int off = 32; off; off >>= 1) v += __shfl_xor(v, off);
            if ((tid & 63) == 0) red[grp][j][wig] = v;
        }
        __syncthreads();
        if (tid < 16) {
            int g2 = tid >> 3, j = tid & 7;
            sc[g2 * 48 + it * 8 + j] = scale * (red[g2][j][0] + red[g2][j][1]);
        }
        __syncthreads();
    }

    // softmax over 96 scores (wave 0)
    if (tid < 64) {
        float s0 = sc[tid];
        float s1 = (tid < 32) ? sc[64 + tid] : -1e30f;
        float m = fmaxf(s0, s1);
#pragma unroll
        for (int off = 32; off; off >>= 1) m = fmaxf(m, __shfl_xor(m, off));
        float p0 = expf(s0 - m);
        float p1 = (tid < 32) ? expf(s1 - m) : 0.f;
        float ssum = p0 + p1;
#pragma unroll
        for (int off = 32; off; off >>= 1) ssum += __shfl_xor(ssum, off);
        float inv = 1.f / ssum;
        sc[tid] = p0 * inv;
        if (tid < 32) sc[64 + tid] = p1 * inv;
    }
    __syncthreads();

    if (tid < ND) {
        float acc = 0.f;
        for (int l = 0; l < NL; ++l) acc += sc[l] * Hb[l * ND + tid];
        ht[b * ND + tid] = acc;
    }
}

// ---------------------------------------------------------------- gates GEMM
// gates(B x 2048) = [h_t | h] (B x 640) @ [W[:,t,:] ; U[:,t,:]] (640 x 2048)
__global__ __launch_bounds__(256, 2) void k_gates(const float* __restrict__ ht,
                                                  const float* __restrict__ h,
                                                  const float* __restrict__ W,
                                                  const float* __restrict__ U,
                                                  float* __restrict__ gates, int t) {
    constexpr int BM = 64, BN = 64, BK = 16;
    __shared__ float As[BK][68];    // padded for float4-aligned rows
    __shared__ float Bs[BK][BN];
    int tid = threadIdx.x;
    int tx = tid & 15, ty = tid >> 4;
    int bm = blockIdx.x * BM, bn = blockIdx.y * BN;
    float acc[4][4] = {};
    for (int kt = 0; kt < 40; ++kt) {
        int kbase = kt * BK;
#pragma unroll
        for (int i = 0; i < 4; ++i) {
            int idx = tid + i * 256;
            int m = idx >> 4, kk = idx & 15;
            int k = kbase + kk;
            float v = (k < ND) ? ht[(bm + m) * ND + k] : h[(bm + m) * NHS + (k - ND)];
            As[kk][m] = v;
        }
#pragma unroll
        for (int i = 0; i < 4; ++i) {
            int idx = tid + i * 256;
            int kk = idx >> 6, nn = idx & 63;
            int k = kbase + kk;
            const float* src = (k < ND) ? (W + (size_t)k * (NT * NG4))
                                        : (U + (size_t)(k - ND) * (NT * NG4));
            Bs[kk][nn] = src[t * NG4 + bn + nn];
        }
        __syncthreads();
#pragma unroll
        for (int kk = 0; kk < BK; ++kk) {
            float4 a = *(const float4*)&As[kk][ty * 4];
            float4 bv = *(const float4*)&Bs[kk][tx * 4];
            float av[4] = {a.x, a.y, a.z, a.w};
            float bb[4] = {bv.x, bv.y, bv.z, bv.w};
#pragma unroll
            for (int i = 0; i < 4; ++i)
#pragma unroll
                for (int j = 0; j < 4; ++j) acc[i][j] += av[i] * bb[j];
        }
        __syncthreads();
    }
#pragma unroll
    for (int i = 0; i < 4; ++i) {
        int row = bm + ty * 4 + i;
        float4 v = make_float4(acc[i][0], acc[i][1], acc[i][2], acc[i][3]);
        *(float4*)&gates[(size_t)row * NG4 + bn + tx * 4] = v;
    }
}

// ---------------------------------------------------------------- cell update + y head
__global__ __launch_bounds__(512) void k_cell(const float* __restrict__ g,
                                              const float* __restrict__ bias,
                                              const float* __restrict__ Wy,
                                              const float* __restrict__ fcw,
                                              const float* __restrict__ fcb,
                                              float* __restrict__ c,
                                              float* __restrict__ h,
                                              float* __restrict__ y,
                                              float* __restrict__ out_y,
                                              float* __restrict__ out_h, int t) {
    int b = blockIdx.x, s = threadIdx.x;
    float yp = y[b];
    int gb = b * NG4;
    int bb = t * NG4;
    float gi = g[gb + s]            + bias[bb + s]            + yp * Wy[bb + s];
    float gf = g[gb + NHS + s]      + bias[bb + NHS + s]      + yp * Wy[bb + NHS + s];
    float gg = g[gb + 2 * NHS + s]  + bias[bb + 2 * NHS + s]  + yp * Wy[bb + 2 * NHS + s];
    float go = g[gb + 3 * NHS + s]  + bias[bb + 3 * NHS + s]  + yp * Wy[bb + 3 * NHS + s];
    float iv = 1.f / (1.f + expf(-gi));
    float fv = 1.f / (1.f + expf(-gf));
    float gv = tanhf(gg);
    float ov = 1.f / (1.f + expf(-go));
    float cn = fv * c[b * NHS + s] + iv * gv;
    float hn = ov * tanhf(cn);
    c[b * NHS + s] = cn;
    h[b * NHS + s] = hn;
    out_h[(size_t)b * (NT * NHS) + t * NHS + s] = hn;
    float pr = hn * fcw[t * NHS + s];
#pragma unroll
    for (int off = 32; off; off >>= 1) pr += __shfl_xor(pr, off);
    __shared__ float red[8];
    if ((s & 63) == 0) red[s >> 6] = pr;
    __syncthreads();
    if (s == 0) {
        float acc = fcb[t];
#pragma unroll
        for (int w2 = 0; w2 < 8; ++w2) acc += red[w2];
        out_y[b * NT + t] = acc;
        y[b] = acc;
    }
}

// ---------------------------------------------------------------- launcher
extern "C" void kernel_launch(void* const* d_in, const int* in_sizes, int n_in,
                              void* d_out, int out_size, void* d_ws, size_t ws_size,
                              hipStream_t stream) {
    (void)in_sizes; (void)n_in; (void)out_size; (void)ws_size;
    const float* H    = (const float*)d_in[0];
    const float* y0   = (const float*)d_in[1];
    const float* emb  = (const float*)d_in[2];
    // d_in[3] = Y (unused by reference)
    const float* Wa   = (const float*)d_in[4];
    const float* Ua   = (const float*)d_in[5];
    const float* ba   = (const float*)d_in[6];
    const float* Va   = (const float*)d_in[7];
    const float* W    = (const float*)d_in[8];
    const float* U    = (const float*)d_in[9];
    const float* bias = (const float*)d_in[10];
    const float* Wy   = (const float*)d_in[11];
    const float* fcw  = (const float*)d_in[12];
    const float* fcb  = (const float*)d_in[13];
    // d_in[14] = epoch (unused)

    float* out_y = (float*)d_out;              // (B, T)
    float* out_h = out_y + NB * NT;            // (B, T, HS)

    float* ws   = (float*)d_ws;
    float* c_st = ws;                          // B*HS
    float* h_st = c_st + NB * NHS;             // B*HS
    float* y_st = h_st + NB * NHS;             // B
    float* cua  = y_st + NB;                   // B*N
    float* ht   = cua + NB * NN;               // B*D
    float* gts  = ht + NB * ND;                // B*4HS

    hipLaunchKernelGGL(k_init, dim3((NB * NHS) / 256), dim3(256), 0, stream,
                       emb, y0, c_st, h_st, y_st);
    for (int t = 0; t < NT; ++t) {
        hipLaunchKernelGGL(k_cua, dim3(NB / 8), dim3(256), 0, stream, c_st, Ua, cua, t);
        hipLaunchKernelGGL(k_attn, dim3(NB), dim3(256), 0, stream, H, Wa, Va, ba, cua, ht, t);
        hipLaunchKernelGGL(k_gates, dim3(16, 32), dim3(256), 0, stream, ht, h_st, W, U, gts, t);
        hipLaunchKernelGGL(k_cell, dim3(NB), dim3(512), 0, stream,
                           gts, bias, Wy, fcw, fcb, c_st, h_st, y_st, out_y, out_h, t);
    }
}

// Round 2
// 3459.435 us; speedup vs baseline: 2.3496x; 2.3496x over previous
//
#include <hip/hip_runtime.h>
#include <math.h>

// Problem constants
constexpr int NB  = 1024;   // batch
constexpr int NL  = 96;     // seq len L
constexpr int ND  = 128;    // D
constexpr int NHS = 512;    // hidden
constexpr int NT  = 24;     // timesteps
constexpr int NN  = 128;    // attention dim N
constexpr int NG4 = 4 * NHS; // 2048
constexpr int BL  = NB * NL; // 98304

typedef __attribute__((ext_vector_type(8))) short bf16x8;
typedef __attribute__((ext_vector_type(4))) float f32x4;

static __device__ __forceinline__ unsigned short f2b(float x) {
    union { float f; unsigned u; } v; v.f = x;
    unsigned r = v.u + 0x7fffu + ((v.u >> 16) & 1u);   // RNE
    return (unsigned short)(r >> 16);
}
static __device__ __forceinline__ float b2f(unsigned short s) {
    union { unsigned u; float f; } v; v.u = ((unsigned)s) << 16;
    return v.f;
}

// ---------------------------------------------------------------- init state
__global__ __launch_bounds__(256) void k_init(const float* __restrict__ emb,
                                              const float* __restrict__ y0,
                                              float* __restrict__ c,
                                              float* __restrict__ h,
                                              float* __restrict__ y) {
    int idx = blockIdx.x * blockDim.x + threadIdx.x;
    if (idx < NB * NHS) {
        int b = idx / NHS, s = idx - b * NHS;
        h[idx] = emb[b * 2 * NHS + s];
        c[idx] = emb[b * 2 * NHS + NHS + s];
    }
    if (idx < NB) y[idx] = y0[idx];
}

// ---------------------------------------------------------------- H -> bf16
__global__ __launch_bounds__(256) void k_prep(const float* __restrict__ H,
                                              unsigned short* __restrict__ Hbf) {
    int idx = (blockIdx.x * 256 + threadIdx.x) * 8;
    float4 a = *(const float4*)(H + idx);
    float4 b = *(const float4*)(H + idx + 4);
    bf16x8 o;
    o[0] = (short)f2b(a.x); o[1] = (short)f2b(a.y);
    o[2] = (short)f2b(a.z); o[3] = (short)f2b(a.w);
    o[4] = (short)f2b(b.x); o[5] = (short)f2b(b.y);
    o[6] = (short)f2b(b.z); o[7] = (short)f2b(b.w);
    *(bf16x8*)(Hbf + idx) = o;
}

// ---------------------------------------------------------------- Wa -> bf16, [t][n][d] layout
__global__ __launch_bounds__(128) void k_prepwa(const float* __restrict__ Wa,
                                                unsigned short* __restrict__ Wab) {
    int tn = blockIdx.x;          // t*NN + n
    int t = tn / NN, n = tn - t * NN;
    int d = threadIdx.x;
    Wab[(size_t)tn * ND + d] = f2b(Wa[(size_t)d * (NT * NN) + t * NN + n]);
}

// ---------------------------------------------------------------- cUa = c @ Ua[:,t,:]  (+ ba fold)
__global__ __launch_bounds__(256) void k_cua(const float* __restrict__ c,
                                             const float* __restrict__ Ua,
                                             const float* __restrict__ ba,
                                             float* __restrict__ cua, int t) {
    __shared__ float cs[8 * NHS];       // 16 KB
    __shared__ float red[8][NN];        // 4 KB
    int tid = threadIdx.x;
    int b0 = blockIdx.x * 8;
    for (int i = tid; i < 8 * NHS; i += 256) cs[i] = c[b0 * NHS + i];
    __syncthreads();
    int kg = tid >> 7;          // 0/1: K half
    int n  = tid & 127;
    float acc[8] = {0, 0, 0, 0, 0, 0, 0, 0};
    int k0 = kg * 256;
    for (int k = k0; k < k0 + 256; ++k) {
        float ua = Ua[k * (NT * NN) + t * NN + n];
#pragma unroll
        for (int r = 0; r < 8; ++r) acc[r] += cs[r * NHS + k] * ua;
    }
    if (kg == 1) {
#pragma unroll
        for (int r = 0; r < 8; ++r) red[r][n] = acc[r];
    }
    __syncthreads();
    if (kg == 0) {
        float bav = ba[t * NN + n];
#pragma unroll
        for (int r = 0; r < 8; ++r) cua[(b0 + r) * NN + n] = acc[r] + red[r][n] + bav;
    }
}

// ---------------------------------------------------------------- attention scores via MFMA
// score[bl] = scale * sum_n va[n]*tanh( sum_d Hbf[bl,d]*Wab[t,n,d] + cua[b,n](+ba) )
__global__ __launch_bounds__(256, 2) void k_score(const unsigned short* __restrict__ Hbf,
                                                  const unsigned short* __restrict__ Wab,
                                                  const float* __restrict__ Va,
                                                  const float* __restrict__ cua,
                                                  float* __restrict__ score, int t) {
    __shared__ unsigned short Bs[NN][136];   // [n][d], +8 pad -> balanced banks, 34.8 KB
    int tid = threadIdx.x;
    const unsigned short* src = Wab + (size_t)t * NN * ND;
#pragma unroll
    for (int f = tid; f < 2048; f += 256) {      // 2048 chunks of 8 bf16
        int n = f >> 4, d0 = (f & 15) << 3;
        *(bf16x8*)&Bs[n][d0] = *(const bf16x8*)(src + n * ND + d0);
    }
    __syncthreads();

    int lane = tid & 63, wave = tid >> 6;
    int ln = lane & 15, kg = lane >> 4;
    int row_base = blockIdx.x * 64 + wave * 16;
    const unsigned short* Hrow = Hbf + (size_t)(row_base + ln) * ND;

    f32x4 zero = {0.f, 0.f, 0.f, 0.f};
    f32x4 acc[8];
#pragma unroll
    for (int nt = 0; nt < 8; ++nt) acc[nt] = zero;

#pragma unroll
    for (int kc = 0; kc < 4; ++kc) {
        int d0 = kc * 32 + kg * 8;
        bf16x8 a = *(const bf16x8*)(Hrow + d0);
#pragma unroll
        for (int nt = 0; nt < 8; ++nt) {
            bf16x8 bb = *(const bf16x8*)&Bs[nt * 16 + ln][d0];
            acc[nt] = __builtin_amdgcn_mfma_f32_16x16x32_bf16(a, bb, acc[nt], 0, 0, 0);
        }
    }

    float va_l[8];
#pragma unroll
    for (int nt = 0; nt < 8; ++nt) va_l[nt] = Va[(nt * 16 + ln) * NT + t];

    const float scale = 0.044194173824159216f;  // 1/sqrt(512)
#pragma unroll
    for (int r = 0; r < 4; ++r) {
        int row = row_base + kg * 4 + r;
        int b = row / NL;
        const float* cb = cua + b * NN;
        float s = 0.f;
#pragma unroll
        for (int nt = 0; nt < 8; ++nt) {
            float pre = acc[nt][r] + cb[nt * 16 + ln];
            s += va_l[nt] * tanhf(pre);
        }
#pragma unroll
        for (int off = 1; off < 16; off <<= 1) s += __shfl_xor(s, off);
        if (ln == 0) score[row] = s * scale;
    }
}

// ---------------------------------------------------------------- softmax + context
__global__ __launch_bounds__(256) void k_softctx(const unsigned short* __restrict__ Hbf,
                                                 const float* __restrict__ score,
                                                 float* __restrict__ ht) {
    __shared__ float sc[NL];
    __shared__ float red[16][ND];   // 8 KB
    int b = blockIdx.x, tid = threadIdx.x;
    if (tid < 64) {
        float s0 = score[b * NL + tid];
        float s1 = (tid < 32) ? score[b * NL + 64 + tid] : -1e30f;
        float m = fmaxf(s0, s1);
#pragma unroll
        for (int off = 32; off; off >>= 1) m = fmaxf(m, __shfl_xor(m, off));
        float p0 = expf(s0 - m);
        float p1 = (tid < 32) ? expf(s1 - m) : 0.f;
        float ssum = p0 + p1;
#pragma unroll
        for (int off = 32; off; off >>= 1) ssum += __shfl_xor(ssum, off);
        float inv = 1.f / ssum;
        sc[tid] = p0 * inv;
        if (tid < 32) sc[64 + tid] = p1 * inv;
    }
    __syncthreads();

    int dc = tid & 15, lg = tid >> 4;    // 16 l-groups of 6 rows each
    int d0 = dc * 8;
    const unsigned short* Hb = Hbf + (size_t)b * NL * ND;
    float a8[8] = {0, 0, 0, 0, 0, 0, 0, 0};
    for (int i = 0; i < 6; ++i) {
        int l = lg * 6 + i;
        bf16x8 hv = *(const bf16x8*)(Hb + l * ND + d0);
        float w = sc[l];
#pragma unroll
        for (int j = 0; j < 8; ++j) a8[j] += w * b2f((unsigned short)hv[j]);
    }
#pragma unroll
    for (int j = 0; j < 8; ++j) red[lg][d0 + j] = a8[j];
    __syncthreads();
    if (tid < ND) {
        float acc = 0.f;
#pragma unroll
        for (int g = 0; g < 16; ++g) acc += red[g][tid];
        ht[b * ND + tid] = acc;
    }
}

// ---------------------------------------------------------------- gates GEMM (f32)
__global__ __launch_bounds__(256, 2) void k_gates(const float* __restrict__ ht,
                                                  const float* __restrict__ h,
                                                  const float* __restrict__ W,
                                                  const float* __restrict__ U,
                                                  float* __restrict__ gates, int t) {
    constexpr int BM = 64, BN = 64, BK = 16;
    __shared__ float As[BK][68];
    __shared__ float Bs[BK][BN];
    int tid = threadIdx.x;
    int tx = tid & 15, ty = tid >> 4;
    int bm = blockIdx.x * BM, bn = blockIdx.y * BN;
    float acc[4][4] = {};
    for (int kt = 0; kt < 40; ++kt) {
        int kbase = kt * BK;
#pragma unroll
        for (int i = 0; i < 4; ++i) {
            int idx = tid + i * 256;
            int m = idx >> 4, kk = idx & 15;
            int k = kbase + kk;
            float v = (k < ND) ? ht[(bm + m) * ND + k] : h[(bm + m) * NHS + (k - ND)];
            As[kk][m] = v;
        }
#pragma unroll
        for (int i = 0; i < 4; ++i) {
            int idx = tid + i * 256;
            int kk = idx >> 6, nn = idx & 63;
            int k = kbase + kk;
            const float* src = (k < ND) ? (W + (size_t)k * (NT * NG4))
                                        : (U + (size_t)(k - ND) * (NT * NG4));
            Bs[kk][nn] = src[t * NG4 + bn + nn];
        }
        __syncthreads();
#pragma unroll
        for (int kk = 0; kk < BK; ++kk) {
            float4 a = *(const float4*)&As[kk][ty * 4];
            float4 bv = *(const float4*)&Bs[kk][tx * 4];
            float av[4] = {a.x, a.y, a.z, a.w};
            float bb[4] = {bv.x, bv.y, bv.z, bv.w};
#pragma unroll
            for (int i = 0; i < 4; ++i)
#pragma unroll
                for (int j = 0; j < 4; ++j) acc[i][j] += av[i] * bb[j];
        }
        __syncthreads();
    }
#pragma unroll
    for (int i = 0; i < 4; ++i) {
        int row = bm + ty * 4 + i;
        float4 v = make_float4(acc[i][0], acc[i][1], acc[i][2], acc[i][3]);
        *(float4*)&gates[(size_t)row * NG4 + bn + tx * 4] = v;
    }
}

// ---------------------------------------------------------------- cell update + y head
__global__ __launch_bounds__(512) void k_cell(const float* __restrict__ g,
                                              const float* __restrict__ bias,
                                              const float* __restrict__ Wy,
                                              const float* __restrict__ fcw,
                                              const float* __restrict__ fcb,
                                              float* __restrict__ c,
                                              float* __restrict__ h,
                                              float* __restrict__ y,
                                              float* __restrict__ out_y,
                                              float* __restrict__ out_h, int t) {
    int b = blockIdx.x, s = threadIdx.x;
    float yp = y[b];
    int gb = b * NG4;
    int bb = t * NG4;
    float gi = g[gb + s]            + bias[bb + s]            + yp * Wy[bb + s];
    float gf = g[gb + NHS + s]      + bias[bb + NHS + s]      + yp * Wy[bb + NHS + s];
    float gg = g[gb + 2 * NHS + s]  + bias[bb + 2 * NHS + s]  + yp * Wy[bb + 2 * NHS + s];
    float go = g[gb + 3 * NHS + s]  + bias[bb + 3 * NHS + s]  + yp * Wy[bb + 3 * NHS + s];
    float iv = 1.f / (1.f + expf(-gi));
    float fv = 1.f / (1.f + expf(-gf));
    float gv = tanhf(gg);
    float ov = 1.f / (1.f + expf(-go));
    float cn = fv * c[b * NHS + s] + iv * gv;
    float hn = ov * tanhf(cn);
    c[b * NHS + s] = cn;
    h[b * NHS + s] = hn;
    out_h[(size_t)b * (NT * NHS) + t * NHS + s] = hn;
    float pr = hn * fcw[t * NHS + s];
#pragma unroll
    for (int off = 32; off; off >>= 1) pr += __shfl_xor(pr, off);
    __shared__ float red[8];
    if ((s & 63) == 0) red[s >> 6] = pr;
    __syncthreads();
    if (s == 0) {
        float acc = fcb[t];
#pragma unroll
        for (int w2 = 0; w2 < 8; ++w2) acc += red[w2];
        out_y[b * NT + t] = acc;
        y[b] = acc;
    }
}

// ---------------------------------------------------------------- launcher
extern "C" void kernel_launch(void* const* d_in, const int* in_sizes, int n_in,
                              void* d_out, int out_size, void* d_ws, size_t ws_size,
                              hipStream_t stream) {
    (void)in_sizes; (void)n_in; (void)out_size; (void)ws_size;
    const float* H    = (const float*)d_in[0];
    const float* y0   = (const float*)d_in[1];
    const float* emb  = (const float*)d_in[2];
    const float* Wa   = (const float*)d_in[4];
    const float* Ua   = (const float*)d_in[5];
    const float* ba   = (const float*)d_in[6];
    const float* Va   = (const float*)d_in[7];
    const float* W    = (const float*)d_in[8];
    const float* U    = (const float*)d_in[9];
    const float* bias = (const float*)d_in[10];
    const float* Wy   = (const float*)d_in[11];
    const float* fcw  = (const float*)d_in[12];
    const float* fcb  = (const float*)d_in[13];

    float* out_y = (float*)d_out;              // (B, T)
    float* out_h = out_y + NB * NT;            // (B, T, HS)

    float* ws    = (float*)d_ws;
    float* c_st  = ws;                          // B*HS
    float* h_st  = c_st + NB * NHS;             // B*HS
    float* y_st  = h_st + NB * NHS;             // B
    float* cua   = y_st + NB;                   // B*N
    float* ht    = cua + NB * NN;               // B*D
    float* gts   = ht + NB * ND;                // B*4HS
    float* score = gts + NB * NG4;              // B*L
    unsigned short* Hbf = (unsigned short*)(score + BL);       // B*L*D bf16
    unsigned short* Wab = Hbf + (size_t)BL * ND;               // T*N*D bf16

    hipLaunchKernelGGL(k_init, dim3((NB * NHS) / 256), dim3(256), 0, stream,
                       emb, y0, c_st, h_st, y_st);
    hipLaunchKernelGGL(k_prep, dim3(BL * ND / (256 * 8)), dim3(256), 0, stream, H, Hbf);
    hipLaunchKernelGGL(k_prepwa, dim3(NT * NN), dim3(128), 0, stream, Wa, Wab);

    for (int t = 0; t < NT; ++t) {
        hipLaunchKernelGGL(k_cua, dim3(NB / 8), dim3(256), 0, stream, c_st, Ua, ba, cua, t);
        hipLaunchKernelGGL(k_score, dim3(BL / 64), dim3(256), 0, stream,
                           Hbf, Wab, Va, cua, score, t);
        hipLaunchKernelGGL(k_softctx, dim3(NB), dim3(256), 0, stream, Hbf, score, ht);
        hipLaunchKernelGGL(k_gates, dim3(16, 32), dim3(256), 0, stream, ht, h_st, W, U, gts, t);
        hipLaunchKernelGGL(k_cell, dim3(NB), dim3(512), 0, stream,
                           gts, bias, Wy, fcw, fcb, c_st, h_st, y_st, out_y, out_h, t);
    }
}

// Round 3
// 2084.177 us; speedup vs baseline: 3.9000x; 1.6599x over previous
//
#include <hip/hip_runtime.h>
#include <math.h>

// Problem constants
constexpr int NB  = 1024;   // batch
constexpr int NL  = 96;     // seq len L
constexpr int ND  = 128;    // D
constexpr int NHS = 512;    // hidden
constexpr int NT  = 24;     // timesteps
constexpr int NN  = 128;    // attention dim N
constexpr int NG4 = 4 * NHS; // 2048
constexpr int NK  = ND + NHS; // 640 concat K
constexpr int BL  = NB * NL; // 98304

typedef __attribute__((ext_vector_type(8))) short bf16x8;
typedef __attribute__((ext_vector_type(4))) float f32x4;

static __device__ __forceinline__ unsigned short f2b(float x) {
    union { float f; unsigned u; } v; v.f = x;
    unsigned r = v.u + 0x7fffu + ((v.u >> 16) & 1u);   // RNE
    return (unsigned short)(r >> 16);
}
static __device__ __forceinline__ float b2f(unsigned short s) {
    union { unsigned u; float f; } v; v.u = ((unsigned)s) << 16;
    return v.f;
}

// ---------------------------------------------------------------- init state
__global__ __launch_bounds__(256) void k_init(const float* __restrict__ emb,
                                              const float* __restrict__ y0,
                                              float* __restrict__ c,
                                              unsigned short* __restrict__ Abuf,
                                              float* __restrict__ y) {
    int idx = blockIdx.x * blockDim.x + threadIdx.x;
    if (idx < NB * NHS) {
        int b = idx / NHS, s = idx - b * NHS;
        Abuf[(size_t)b * NK + ND + s] = f2b(emb[b * 2 * NHS + s]);
        c[idx] = emb[b * 2 * NHS + NHS + s];
    }
    if (idx < NB) y[idx] = y0[idx];
}

// ---------------------------------------------------------------- H -> bf16
__global__ __launch_bounds__(256) void k_prep(const float* __restrict__ H,
                                              unsigned short* __restrict__ Hbf) {
    int idx = (blockIdx.x * 256 + threadIdx.x) * 8;
    float4 a = *(const float4*)(H + idx);
    float4 b = *(const float4*)(H + idx + 4);
    bf16x8 o;
    o[0] = (short)f2b(a.x); o[1] = (short)f2b(a.y);
    o[2] = (short)f2b(a.z); o[3] = (short)f2b(a.w);
    o[4] = (short)f2b(b.x); o[5] = (short)f2b(b.y);
    o[6] = (short)f2b(b.z); o[7] = (short)f2b(b.w);
    *(bf16x8*)(Hbf + idx) = o;
}

// ---------------------------------------------------------------- Wa -> bf16, [t][n][d] layout
__global__ __launch_bounds__(128) void k_prepwa(const float* __restrict__ Wa,
                                                unsigned short* __restrict__ Wab) {
    int tn = blockIdx.x;          // t*NN + n
    int t = tn / NN, n = tn - t * NN;
    int d = threadIdx.x;
    Wab[(size_t)tn * ND + d] = f2b(Wa[(size_t)d * (NT * NN) + t * NN + n]);
}

// ---------------------------------------------------------------- W,U -> bf16 Wg[t][n][k], k = [W rows | U rows]
// grid: (t, kc, nc) ; 64x64 tile transpose via LDS
__global__ __launch_bounds__(256) void k_prepw(const float* __restrict__ W,
                                               const float* __restrict__ U,
                                               unsigned short* __restrict__ Wg) {
    __shared__ unsigned short ts[64][66];
    int t  = blockIdx.x;
    int kc = blockIdx.y;    // 0..9
    int nc = blockIdx.z;    // 0..31
    int tid = threadIdx.x;
    // read 64 k-rows x 64 n f32, coalesced along n
    int rowt = tid >> 4;         // 0..15
    int n4   = (tid & 15) << 2;  // 0..60 step 4
#pragma unroll
    for (int i = 0; i < 4; ++i) {
        int kl = i * 16 + rowt;
        int k  = kc * 64 + kl;
        const float* src = (k < ND) ? (W + (size_t)k * (NT * NG4))
                                    : (U + (size_t)(k - ND) * (NT * NG4));
        float4 v = *(const float4*)&src[t * NG4 + nc * 64 + n4];
        ts[kl][n4 + 0] = f2b(v.x);
        ts[kl][n4 + 1] = f2b(v.y);
        ts[kl][n4 + 2] = f2b(v.z);
        ts[kl][n4 + 3] = f2b(v.w);
    }
    __syncthreads();
    // write 64 n-rows x 64 k bf16, contiguous k
#pragma unroll
    for (int p = 0; p < 2; ++p) {
        int flat = p * 256 + tid;
        int nl = flat >> 3, k8 = (flat & 7) << 3;
        bf16x8 o;
#pragma unroll
        for (int j = 0; j < 8; ++j) o[j] = (short)ts[k8 + j][nl];
        *(bf16x8*)&Wg[((size_t)(t * NG4 + nc * 64 + nl)) * NK + kc * 64 + k8] = o;
    }
}

// ---------------------------------------------------------------- cUa = c @ Ua[:,t,:]  (+ ba fold)
__global__ __launch_bounds__(256) void k_cua(const float* __restrict__ c,
                                             const float* __restrict__ Ua,
                                             const float* __restrict__ ba,
                                             float* __restrict__ cua, int t) {
    __shared__ float cs[8 * NHS];       // 16 KB
    __shared__ float red[8][NN];        // 4 KB
    int tid = threadIdx.x;
    int b0 = blockIdx.x * 8;
    for (int i = tid; i < 8 * NHS; i += 256) cs[i] = c[b0 * NHS + i];
    __syncthreads();
    int kg = tid >> 7;          // 0/1: K half
    int n  = tid & 127;
    float acc[8] = {0, 0, 0, 0, 0, 0, 0, 0};
    int k0 = kg * 256;
    for (int k = k0; k < k0 + 256; ++k) {
        float ua = Ua[k * (NT * NN) + t * NN + n];
#pragma unroll
        for (int r = 0; r < 8; ++r) acc[r] += cs[r * NHS + k] * ua;
    }
    if (kg == 1) {
#pragma unroll
        for (int r = 0; r < 8; ++r) red[r][n] = acc[r];
    }
    __syncthreads();
    if (kg == 0) {
        float bav = ba[t * NN + n];
#pragma unroll
        for (int r = 0; r < 8; ++r) cua[(b0 + r) * NN + n] = acc[r] + red[r][n] + bav;
    }
}

// ---------------------------------------------------------------- attention scores via MFMA
__global__ __launch_bounds__(256, 2) void k_score(const unsigned short* __restrict__ Hbf,
                                                  const unsigned short* __restrict__ Wab,
                                                  const float* __restrict__ Va,
                                                  const float* __restrict__ cua,
                                                  float* __restrict__ score, int t) {
    __shared__ unsigned short Bs[NN][136];   // [n][d]
    int tid = threadIdx.x;
    const unsigned short* src = Wab + (size_t)t * NN * ND;
#pragma unroll
    for (int f = tid; f < 2048; f += 256) {
        int n = f >> 4, d0 = (f & 15) << 3;
        *(bf16x8*)&Bs[n][d0] = *(const bf16x8*)(src + n * ND + d0);
    }
    __syncthreads();

    int lane = tid & 63, wave = tid >> 6;
    int ln = lane & 15, kg = lane >> 4;
    int row_base = blockIdx.x * 64 + wave * 16;
    const unsigned short* Hrow = Hbf + (size_t)(row_base + ln) * ND;

    f32x4 zero = {0.f, 0.f, 0.f, 0.f};
    f32x4 acc[8];
#pragma unroll
    for (int nt = 0; nt < 8; ++nt) acc[nt] = zero;

#pragma unroll
    for (int kc = 0; kc < 4; ++kc) {
        int d0 = kc * 32 + kg * 8;
        bf16x8 a = *(const bf16x8*)(Hrow + d0);
#pragma unroll
        for (int nt = 0; nt < 8; ++nt) {
            bf16x8 bb = *(const bf16x8*)&Bs[nt * 16 + ln][d0];
            acc[nt] = __builtin_amdgcn_mfma_f32_16x16x32_bf16(a, bb, acc[nt], 0, 0, 0);
        }
    }

    float va_l[8];
#pragma unroll
    for (int nt = 0; nt < 8; ++nt) va_l[nt] = Va[(nt * 16 + ln) * NT + t];

    const float scale = 0.044194173824159216f;  // 1/sqrt(512)
#pragma unroll
    for (int r = 0; r < 4; ++r) {
        int row = row_base + kg * 4 + r;
        int b = row / NL;
        const float* cb = cua + b * NN;
        float s = 0.f;
#pragma unroll
        for (int nt = 0; nt < 8; ++nt) {
            float pre = acc[nt][r] + cb[nt * 16 + ln];
            s += va_l[nt] * tanhf(pre);
        }
#pragma unroll
        for (int off = 1; off < 16; off <<= 1) s += __shfl_xor(s, off);
        if (ln == 0) score[row] = s * scale;
    }
}

// ---------------------------------------------------------------- softmax + context -> Abuf[:, 0:128] bf16
__global__ __launch_bounds__(256) void k_softctx(const unsigned short* __restrict__ Hbf,
                                                 const float* __restrict__ score,
                                                 unsigned short* __restrict__ Abuf) {
    __shared__ float sc[NL];
    __shared__ float red[16][ND];   // 8 KB
    int b = blockIdx.x, tid = threadIdx.x;
    if (tid < 64) {
        float s0 = score[b * NL + tid];
        float s1 = (tid < 32) ? score[b * NL + 64 + tid] : -1e30f;
        float m = fmaxf(s0, s1);
#pragma unroll
        for (int off = 32; off; off >>= 1) m = fmaxf(m, __shfl_xor(m, off));
        float p0 = expf(s0 - m);
        float p1 = (tid < 32) ? expf(s1 - m) : 0.f;
        float ssum = p0 + p1;
#pragma unroll
        for (int off = 32; off; off >>= 1) ssum += __shfl_xor(ssum, off);
        float inv = 1.f / ssum;
        sc[tid] = p0 * inv;
        if (tid < 32) sc[64 + tid] = p1 * inv;
    }
    __syncthreads();

    int dc = tid & 15, lg = tid >> 4;
    int d0 = dc * 8;
    const unsigned short* Hb = Hbf + (size_t)b * NL * ND;
    float a8[8] = {0, 0, 0, 0, 0, 0, 0, 0};
    for (int i = 0; i < 6; ++i) {
        int l = lg * 6 + i;
        bf16x8 hv = *(const bf16x8*)(Hb + l * ND + d0);
        float w = sc[l];
#pragma unroll
        for (int j = 0; j < 8; ++j) a8[j] += w * b2f((unsigned short)hv[j]);
    }
#pragma unroll
    for (int j = 0; j < 8; ++j) red[lg][d0 + j] = a8[j];
    __syncthreads();
    if (tid < ND) {
        float acc = 0.f;
#pragma unroll
        for (int g = 0; g < 16; ++g) acc += red[g][tid];
        Abuf[(size_t)b * NK + tid] = f2b(acc);
    }
}

// ---------------------------------------------------------------- gates GEMM via MFMA
// gates(1024 x 2048) = Abuf(1024 x 640 bf16) @ Wg[t](2048 x 640 bf16, [n][k])^T
__global__ __launch_bounds__(256, 2) void k_gates2(const unsigned short* __restrict__ Abuf,
                                                   const unsigned short* __restrict__ Wg,
                                                   float* __restrict__ gates, int t) {
    __shared__ unsigned short Bs[NN][136];   // [n][k-chunk], 34.8 KB
    int tid = threadIdx.x;
    int lane = tid & 63, wave = tid >> 6;
    int ln = lane & 15, kg = lane >> 4;
    int m0 = blockIdx.x * 64;
    int n0 = blockIdx.y * NN;
    const unsigned short* Wt = Wg + (size_t)(t * NG4 + n0) * NK;
    const unsigned short* Arow = Abuf + (size_t)(m0 + wave * 16 + ln) * NK;

    f32x4 zero = {0.f, 0.f, 0.f, 0.f};
    f32x4 acc[8];
#pragma unroll
    for (int nt = 0; nt < 8; ++nt) acc[nt] = zero;

    for (int kc = 0; kc < 5; ++kc) {        // K chunks of 128
        __syncthreads();
#pragma unroll
        for (int it = 0; it < 8; ++it) {
            int flat = it * 256 + tid;
            int n = flat >> 4, k8 = (flat & 15) << 3;
            *(bf16x8*)&Bs[n][k8] = *(const bf16x8*)(Wt + (size_t)n * NK + kc * 128 + k8);
        }
        __syncthreads();
#pragma unroll
        for (int j8 = 0; j8 < 4; ++j8) {    // K sub-steps of 32
            int d0 = j8 * 32 + kg * 8;
            bf16x8 a = *(const bf16x8*)(Arow + kc * 128 + d0);
#pragma unroll
            for (int nt = 0; nt < 8; ++nt) {
                bf16x8 bb = *(const bf16x8*)&Bs[nt * 16 + ln][d0];
                acc[nt] = __builtin_amdgcn_mfma_f32_16x16x32_bf16(a, bb, acc[nt], 0, 0, 0);
            }
        }
    }
#pragma unroll
    for (int nt = 0; nt < 8; ++nt) {
#pragma unroll
        for (int r = 0; r < 4; ++r) {
            int row = m0 + wave * 16 + kg * 4 + r;
            gates[(size_t)row * NG4 + n0 + nt * 16 + ln] = acc[nt][r];
        }
    }
}

// ---------------------------------------------------------------- cell update + y head
__global__ __launch_bounds__(512) void k_cell(const float* __restrict__ g,
                                              const float* __restrict__ bias,
                                              const float* __restrict__ Wy,
                                              const float* __restrict__ fcw,
                                              const float* __restrict__ fcb,
                                              float* __restrict__ c,
                                              unsigned short* __restrict__ Abuf,
                                              float* __restrict__ y,
                                              float* __restrict__ out_y,
                                              float* __restrict__ out_h, int t) {
    int b = blockIdx.x, s = threadIdx.x;
    float yp = y[b];
    int gb = b * NG4;
    int bb = t * NG4;
    float gi = g[gb + s]            + bias[bb + s]            + yp * Wy[bb + s];
    float gf = g[gb + NHS + s]      + bias[bb + NHS + s]      + yp * Wy[bb + NHS + s];
    float gg = g[gb + 2 * NHS + s]  + bias[bb + 2 * NHS + s]  + yp * Wy[bb + 2 * NHS + s];
    float go = g[gb + 3 * NHS + s]  + bias[bb + 3 * NHS + s]  + yp * Wy[bb + 3 * NHS + s];
    float iv = 1.f / (1.f + expf(-gi));
    float fv = 1.f / (1.f + expf(-gf));
    float gv = tanhf(gg);
    float ov = 1.f / (1.f + expf(-go));
    float cn = fv * c[b * NHS + s] + iv * gv;
    float hn = ov * tanhf(cn);
    c[b * NHS + s] = cn;
    Abuf[(size_t)b * NK + ND + s] = f2b(hn);
    out_h[(size_t)b * (NT * NHS) + t * NHS + s] = hn;
    float pr = hn * fcw[t * NHS + s];
#pragma unroll
    for (int off = 32; off; off >>= 1) pr += __shfl_xor(pr, off);
    __shared__ float red[8];
    if ((s & 63) == 0) red[s >> 6] = pr;
    __syncthreads();
    if (s == 0) {
        float acc = fcb[t];
#pragma unroll
        for (int w2 = 0; w2 < 8; ++w2) acc += red[w2];
        out_y[b * NT + t] = acc;
        y[b] = acc;
    }
}

// ---------------------------------------------------------------- launcher
extern "C" void kernel_launch(void* const* d_in, const int* in_sizes, int n_in,
                              void* d_out, int out_size, void* d_ws, size_t ws_size,
                              hipStream_t stream) {
    (void)in_sizes; (void)n_in; (void)out_size; (void)ws_size;
    const float* H    = (const float*)d_in[0];
    const float* y0   = (const float*)d_in[1];
    const float* emb  = (const float*)d_in[2];
    const float* Wa   = (const float*)d_in[4];
    const float* Ua   = (const float*)d_in[5];
    const float* ba   = (const float*)d_in[6];
    const float* Va   = (const float*)d_in[7];
    const float* W    = (const float*)d_in[8];
    const float* U    = (const float*)d_in[9];
    const float* bias = (const float*)d_in[10];
    const float* Wy   = (const float*)d_in[11];
    const float* fcw  = (const float*)d_in[12];
    const float* fcb  = (const float*)d_in[13];

    float* out_y = (float*)d_out;              // (B, T)
    float* out_h = out_y + NB * NT;            // (B, T, HS)

    float* ws    = (float*)d_ws;
    float* c_st  = ws;                                   // B*HS f32
    float* y_st  = c_st + NB * NHS;                      // B
    float* cua   = y_st + NB;                            // B*N
    float* gts   = cua + NB * NN;                        // B*4HS
    float* score = gts + NB * NG4;                       // B*L
    unsigned short* Hbf  = (unsigned short*)(score + BL);      // B*L*D bf16
    unsigned short* Wab  = Hbf + (size_t)BL * ND;              // T*N*D bf16
    unsigned short* Abuf = Wab + (size_t)NT * NN * ND;         // B*640 bf16
    unsigned short* Wg   = Abuf + (size_t)NB * NK;             // T*2048*640 bf16 (63 MB)

    hipLaunchKernelGGL(k_init, dim3((NB * NHS) / 256), dim3(256), 0, stream,
                       emb, y0, c_st, Abuf, y_st);
    hipLaunchKernelGGL(k_prep, dim3(BL * ND / (256 * 8)), dim3(256), 0, stream, H, Hbf);
    hipLaunchKernelGGL(k_prepwa, dim3(NT * NN), dim3(128), 0, stream, Wa, Wab);
    hipLaunchKernelGGL(k_prepw, dim3(NT, 10, 32), dim3(256), 0, stream, W, U, Wg);

    for (int t = 0; t < NT; ++t) {
        hipLaunchKernelGGL(k_cua, dim3(NB / 8), dim3(256), 0, stream, c_st, Ua, ba, cua, t);
        hipLaunchKernelGGL(k_score, dim3(BL / 64), dim3(256), 0, stream,
                           Hbf, Wab, Va, cua, score, t);
        hipLaunchKernelGGL(k_softctx, dim3(NB), dim3(256), 0, stream, Hbf, score, Abuf);
        hipLaunchKernelGGL(k_gates2, dim3(16, 16), dim3(256), 0, stream, Abuf, Wg, gts, t);
        hipLaunchKernelGGL(k_cell, dim3(NB), dim3(512), 0, stream,
                           gts, bias, Wy, fcw, fcb, c_st, Abuf, y_st, out_y, out_h, t);
    }
}

// Round 4
// 1598.615 us; speedup vs baseline: 5.0846x; 1.3037x over previous
//
#include <hip/hip_runtime.h>
#include <math.h>

// Problem constants
constexpr int NB  = 1024;   // batch
constexpr int NL  = 96;     // seq len L
constexpr int ND  = 128;    // D
constexpr int NHS = 512;    // hidden
constexpr int NT  = 24;     // timesteps
constexpr int NN  = 128;    // attention dim N
constexpr int NG4 = 4 * NHS; // 2048
constexpr int NK  = ND + NHS; // 640 concat K
constexpr int BL  = NB * NL; // 98304

typedef __attribute__((ext_vector_type(8))) short bf16x8;
typedef __attribute__((ext_vector_type(4))) float f32x4;

static __device__ __forceinline__ unsigned short f2b(float x) {
    union { float f; unsigned u; } v; v.f = x;
    unsigned r = v.u + 0x7fffu + ((v.u >> 16) & 1u);   // RNE
    return (unsigned short)(r >> 16);
}
static __device__ __forceinline__ float b2f(unsigned short s) {
    union { unsigned u; float f; } v; v.u = ((unsigned)s) << 16;
    return v.f;
}

// ---------------------------------------------------------------- init state
__global__ __launch_bounds__(256) void k_init(const float* __restrict__ emb,
                                              const float* __restrict__ y0,
                                              float* __restrict__ c,
                                              unsigned short* __restrict__ Ab0,
                                              float* __restrict__ y) {
    int idx = blockIdx.x * blockDim.x + threadIdx.x;
    if (idx < NB * NHS) {
        int b = idx / NHS, s = idx - b * NHS;
        Ab0[(size_t)b * NK + ND + s] = f2b(emb[b * 2 * NHS + s]);
        c[idx] = emb[b * 2 * NHS + NHS + s];
    }
    if (idx < NB) y[idx] = y0[idx];
}

// ---------------------------------------------------------------- H -> bf16
__global__ __launch_bounds__(256) void k_prep(const float* __restrict__ H,
                                              unsigned short* __restrict__ Hbf) {
    int idx = (blockIdx.x * 256 + threadIdx.x) * 8;
    float4 a = *(const float4*)(H + idx);
    float4 b = *(const float4*)(H + idx + 4);
    bf16x8 o;
    o[0] = (short)f2b(a.x); o[1] = (short)f2b(a.y);
    o[2] = (short)f2b(a.z); o[3] = (short)f2b(a.w);
    o[4] = (short)f2b(b.x); o[5] = (short)f2b(b.y);
    o[6] = (short)f2b(b.z); o[7] = (short)f2b(b.w);
    *(bf16x8*)(Hbf + idx) = o;
}

// ---------------------------------------------------------------- Wa -> bf16, [t][n][d] layout
__global__ __launch_bounds__(128) void k_prepwa(const float* __restrict__ Wa,
                                                unsigned short* __restrict__ Wab) {
    int tn = blockIdx.x;          // t*NN + n
    int t = tn / NN, n = tn - t * NN;
    int d = threadIdx.x;
    Wab[(size_t)tn * ND + d] = f2b(Wa[(size_t)d * (NT * NN) + t * NN + n]);
}

// ---------------------------------------------------------------- W,U -> bf16 Wg[t][n][k]
// grid: (nc, kc, t) — nc fastest for contiguous row reads
__global__ __launch_bounds__(256) void k_prepw(const float* __restrict__ W,
                                               const float* __restrict__ U,
                                               unsigned short* __restrict__ Wg) {
    __shared__ unsigned short ts[64][66];
    int nc = blockIdx.x;    // 0..31
    int kc = blockIdx.y;    // 0..9
    int t  = blockIdx.z;    // 0..23
    int tid = threadIdx.x;
    int rowt = tid >> 4;         // 0..15
    int n4   = (tid & 15) << 2;  // 0..60 step 4
#pragma unroll
    for (int i = 0; i < 4; ++i) {
        int kl = i * 16 + rowt;
        int k  = kc * 64 + kl;
        const float* src = (k < ND) ? (W + (size_t)k * (NT * NG4))
                                    : (U + (size_t)(k - ND) * (NT * NG4));
        float4 v = *(const float4*)&src[t * NG4 + nc * 64 + n4];
        ts[kl][n4 + 0] = f2b(v.x);
        ts[kl][n4 + 1] = f2b(v.y);
        ts[kl][n4 + 2] = f2b(v.z);
        ts[kl][n4 + 3] = f2b(v.w);
    }
    __syncthreads();
#pragma unroll
    for (int p = 0; p < 2; ++p) {
        int flat = p * 256 + tid;
        int nl = flat >> 3, k8 = (flat & 7) << 3;
        bf16x8 o;
#pragma unroll
        for (int j = 0; j < 8; ++j) o[j] = (short)ts[k8 + j][nl];
        *(bf16x8*)&Wg[((size_t)(t * NG4 + nc * 64 + nl)) * NK + kc * 64 + k8] = o;
    }
}

// ---------------------------------------------------------------- step-0 cua partials
// cua_part[b][p][n] = sum_{k in p-th 128-chunk} c[b,k] * Ua[k,0,n]
__global__ __launch_bounds__(256) void k_cua0(const float* __restrict__ c,
                                              const float* __restrict__ Ua,
                                              float* __restrict__ cua_part) {
    __shared__ float cs[16][132];
    int m0 = blockIdx.x * 16, n0 = blockIdx.y;
    int tid = threadIdx.x;
#pragma unroll
    for (int i = 0; i < 8; ++i) {
        int idx = tid + i * 256;
        int row = idx >> 7, k = idx & 127;
        cs[row][k] = c[(size_t)(m0 + row) * NHS + n0 * 128 + k];
    }
    __syncthreads();
    int n = tid & 127, rg = tid >> 7;
    float a8[8] = {0, 0, 0, 0, 0, 0, 0, 0};
    for (int k = 0; k < 128; ++k) {
        float ua = Ua[(size_t)(n0 * 128 + k) * (NT * NN) + n];  // t = 0
#pragma unroll
        for (int i = 0; i < 8; ++i) a8[i] += cs[rg * 8 + i][k] * ua;
    }
#pragma unroll
    for (int i = 0; i < 8; ++i)
        cua_part[((size_t)(m0 + rg * 8 + i) * 4 + n0) * 128 + n] = a8[i];
}

// ---------------------------------------------------------------- fused attention (one block per b)
__global__ __launch_bounds__(384, 2) void k_attn_fused(
        const unsigned short* __restrict__ Hbf,
        const unsigned short* __restrict__ Wab,
        const float* __restrict__ Va,
        const float* __restrict__ ba,
        const float* __restrict__ cua_part,
        const float* __restrict__ fcb,
        const float* __restrict__ y_part,
        float* __restrict__ y_st,
        float* __restrict__ out_y,
        unsigned short* __restrict__ Ab,     // ping buffer for step t
        int t) {
    __shared__ unsigned short Ws[NN][136];   // 34.8 KB
    __shared__ float sc[NL];
    __shared__ float cua_s[NN];
    __shared__ float red[24][ND];            // 12.3 KB
    int tid = threadIdx.x;
    int b = blockIdx.x;

    // stage Wa[t] (n-major, d contiguous)
    const unsigned short* src = Wab + (size_t)t * NN * ND;
    for (int f = tid; f < 2048; f += 384) {
        int n = f >> 4, d0 = (f & 15) << 3;
        *(bf16x8*)&Ws[n][d0] = *(const bf16x8*)(src + n * ND + d0);
    }
    // sum cua partials (+ba fold)
    if (tid < 128) {
        const float* cp = cua_part + (size_t)b * 4 * 128 + tid;
        cua_s[tid] = cp[0] + cp[128] + cp[256] + cp[384] + ba[t * NN + tid];
    }
    // finalize y[t-1]
    if (t > 0 && tid == 383) {
        const float* yp = y_part + b * 4;
        float yv = fcb[t - 1] + yp[0] + yp[1] + yp[2] + yp[3];
        y_st[b] = yv;
        out_y[b * NT + (t - 1)] = yv;
    }
    __syncthreads();

    // MFMA scores: 6 waves, wave w -> rows 16w..16w+15 of this b
    int lane = tid & 63, wave = tid >> 6;
    int ln = lane & 15, kg = lane >> 4;
    const unsigned short* Hrow = Hbf + ((size_t)b * NL + wave * 16 + ln) * ND;

    f32x4 zero = {0.f, 0.f, 0.f, 0.f};
    f32x4 acc[8];
#pragma unroll
    for (int nt = 0; nt < 8; ++nt) acc[nt] = zero;
#pragma unroll
    for (int kc = 0; kc < 4; ++kc) {
        int d0 = kc * 32 + kg * 8;
        bf16x8 a = *(const bf16x8*)(Hrow + d0);
#pragma unroll
        for (int nt = 0; nt < 8; ++nt) {
            bf16x8 bb = *(const bf16x8*)&Ws[nt * 16 + ln][d0];
            acc[nt] = __builtin_amdgcn_mfma_f32_16x16x32_bf16(a, bb, acc[nt], 0, 0, 0);
        }
    }
    float va_l[8];
#pragma unroll
    for (int nt = 0; nt < 8; ++nt) va_l[nt] = Va[(nt * 16 + ln) * NT + t];
    const float scale = 0.044194173824159216f;  // 1/sqrt(512)
#pragma unroll
    for (int r = 0; r < 4; ++r) {
        float s = 0.f;
#pragma unroll
        for (int nt = 0; nt < 8; ++nt) {
            float pre = acc[nt][r] + cua_s[nt * 16 + ln];
            s += va_l[nt] * tanhf(pre);
        }
#pragma unroll
        for (int off = 1; off < 16; off <<= 1) s += __shfl_xor(s, off);
        if (ln == 0) sc[wave * 16 + kg * 4 + r] = s * scale;
    }
    __syncthreads();

    // softmax over 96 (wave 0)
    if (tid < 64) {
        float s0 = sc[tid];
        float s1 = (tid < 32) ? sc[64 + tid] : -1e30f;
        float m = fmaxf(s0, s1);
#pragma unroll
        for (int off = 32; off; off >>= 1) m = fmaxf(m, __shfl_xor(m, off));
        float p0 = expf(s0 - m);
        float p1 = (tid < 32) ? expf(s1 - m) : 0.f;
        float ssum = p0 + p1;
#pragma unroll
        for (int off = 32; off; off >>= 1) ssum += __shfl_xor(ssum, off);
        float inv = 1.f / ssum;
        sc[tid] = p0 * inv;
        if (tid < 32) sc[64 + tid] = p1 * inv;
    }
    __syncthreads();

    // context: 24 l-groups x 16 d-chunks
    int dc = tid & 15, lg = tid >> 4;
    int d0 = dc * 8;
    const unsigned short* Hb = Hbf + (size_t)b * NL * ND;
    float a8[8] = {0, 0, 0, 0, 0, 0, 0, 0};
#pragma unroll
    for (int i = 0; i < 4; ++i) {
        int l = lg * 4 + i;
        bf16x8 hv = *(const bf16x8*)(Hb + l * ND + d0);
        float w = sc[l];
#pragma unroll
        for (int j = 0; j < 8; ++j) a8[j] += w * b2f((unsigned short)hv[j]);
    }
#pragma unroll
    for (int j = 0; j < 8; ++j) red[lg][d0 + j] = a8[j];
    __syncthreads();
    if (tid < ND) {
        float accd = 0.f;
#pragma unroll
        for (int g = 0; g < 24; ++g) accd += red[g][tid];
        Ab[(size_t)b * NK + tid] = f2b(accd);
    }
}

// ---------------------------------------------------------------- fused gates GEMM + cell update
// grid (64, 4): block = rows m0..m0+15, s-slice n0*128..+128 across all 4 gates.
// wave w computes gate w. Also emits y partials and cua partials for t+1.
__global__ __launch_bounds__(256, 2) void k_gates_cell(
        const unsigned short* __restrict__ Ab,   // read: [ht | h] for step t
        unsigned short* __restrict__ AbN,        // write: h for step t+1
        const unsigned short* __restrict__ Wg,
        const float* __restrict__ bias,
        const float* __restrict__ Wy,
        const float* __restrict__ fcw,
        const float* __restrict__ Ua,
        const float* __restrict__ y_st,
        float* __restrict__ c,
        float* __restrict__ out_h,
        float* __restrict__ y_part,
        float* __restrict__ cua_part,
        int t) {
    __shared__ __align__(16) char pool[73728];   // Bst[4][128][72] bf16 / epi arrays
    __shared__ float ys[16];
    __shared__ float yredL[16][2];
    int tid = threadIdx.x;
    int lane = tid & 63, wave = tid >> 6;
    int ln = lane & 15, kg = lane >> 4;
    int m0 = blockIdx.x * 16, n0 = blockIdx.y;

    if (tid < 16) ys[tid] = y_st[m0 + tid];

    unsigned short* BstW = (unsigned short*)pool + wave * (128 * 72);
    const unsigned short* Wt = Wg + (size_t)(t * NG4 + wave * NHS + n0 * 128) * NK;
    const unsigned short* Arow = Ab + (size_t)(m0 + ln) * NK;

    f32x4 zero = {0.f, 0.f, 0.f, 0.f};
    f32x4 acc[8];
#pragma unroll
    for (int nt = 0; nt < 8; ++nt) acc[nt] = zero;

    for (int kb = 0; kb < 10; ++kb) {           // K chunks of 64
#pragma unroll
        for (int i = 0; i < 16; ++i) {          // per-wave stage: 128n x 64k
            int flat = i * 64 + lane;
            int n = flat >> 3, k8 = (flat & 7) << 3;
            *(bf16x8*)&BstW[n * 72 + k8] = *(const bf16x8*)(Wt + (size_t)n * NK + kb * 64 + k8);
        }
#pragma unroll
        for (int kc = 0; kc < 2; ++kc) {
            int d0 = kc * 32 + kg * 8;
            bf16x8 a = *(const bf16x8*)(Arow + kb * 64 + d0);
#pragma unroll
            for (int nt = 0; nt < 8; ++nt) {
                bf16x8 bb = *(const bf16x8*)&BstW[(nt * 16 + ln) * 72 + d0];
                acc[nt] = __builtin_amdgcn_mfma_f32_16x16x32_bf16(a, bb, acc[nt], 0, 0, 0);
            }
        }
    }
    __syncthreads();    // all waves done reading Bst before pool reuse

    float* gs = (float*)pool;                    // [4][16][132] = 33792 B
    float* cs = (float*)(pool + 33792);          // [16][132]
#pragma unroll
    for (int nt = 0; nt < 8; ++nt)
#pragma unroll
        for (int r = 0; r < 4; ++r)
            gs[wave * 2112 + (kg * 4 + r) * 132 + nt * 16 + ln] = acc[nt][r];
    __syncthreads();

    // cell update: thread -> s_loc, 8 rows
    int s_loc = tid & 127, rg = tid >> 7;
    int s_glob = n0 * 128 + s_loc;
    float prow[8];
#pragma unroll
    for (int i = 0; i < 8; ++i) {
        int row = rg * 8 + i;
        int b = m0 + row;
        float yp = ys[row];
        float gi = gs[0 * 2112 + row * 132 + s_loc] + bias[t * NG4 + s_glob]
                 + yp * Wy[t * NG4 + s_glob];
        float gf = gs[1 * 2112 + row * 132 + s_loc] + bias[t * NG4 + NHS + s_glob]
                 + yp * Wy[t * NG4 + NHS + s_glob];
        float gg = gs[2 * 2112 + row * 132 + s_loc] + bias[t * NG4 + 2 * NHS + s_glob]
                 + yp * Wy[t * NG4 + 2 * NHS + s_glob];
        float go = gs[3 * 2112 + row * 132 + s_loc] + bias[t * NG4 + 3 * NHS + s_glob]
                 + yp * Wy[t * NG4 + 3 * NHS + s_glob];
        float iv = 1.f / (1.f + expf(-gi));
        float fv = 1.f / (1.f + expf(-gf));
        float gv = tanhf(gg);
        float ov = 1.f / (1.f + expf(-go));
        float cn = fv * c[(size_t)b * NHS + s_glob] + iv * gv;
        float hn = ov * tanhf(cn);
        c[(size_t)b * NHS + s_glob] = cn;
        cs[row * 132 + s_loc] = cn;
        AbN[(size_t)b * NK + ND + s_glob] = f2b(hn);
        out_h[(size_t)b * (NT * NHS) + t * NHS + s_glob] = hn;
        prow[i] = hn * fcw[t * NHS + s_glob];
    }
    // y partials: reduce each row over this block's 128 s (2 waves per rg)
#pragma unroll
    for (int i = 0; i < 8; ++i) {
        float v = prow[i];
#pragma unroll
        for (int off = 32; off; off >>= 1) v += __shfl_xor(v, off);
        if (lane == 0) yredL[rg * 8 + i][(tid >> 6) & 1] = v;
    }
    __syncthreads();
    if (tid < 16)
        y_part[(size_t)(m0 + tid) * 4 + n0] = yredL[tid][0] + yredL[tid][1];

    // cua partial for step t+1 using fresh c (in cs)
    if (t + 1 < NT) {
        float a8[8] = {0, 0, 0, 0, 0, 0, 0, 0};
        int n = s_loc;
        for (int k = 0; k < 128; ++k) {
            float ua = Ua[(size_t)(n0 * 128 + k) * (NT * NN) + (t + 1) * NN + n];
#pragma unroll
            for (int i = 0; i < 8; ++i) a8[i] += cs[(rg * 8 + i) * 132 + k] * ua;
        }
#pragma unroll
        for (int i = 0; i < 8; ++i)
            cua_part[((size_t)(m0 + rg * 8 + i) * 4 + n0) * 128 + n] = a8[i];
    }
}

// ---------------------------------------------------------------- final y (t = NT-1)
__global__ __launch_bounds__(256) void k_yfin(const float* __restrict__ y_part,
                                              const float* __restrict__ fcb,
                                              float* __restrict__ out_y) {
    int b = blockIdx.x * 256 + threadIdx.x;
    if (b < NB) {
        const float* yp = y_part + (size_t)b * 4;
        out_y[b * NT + (NT - 1)] = fcb[NT - 1] + yp[0] + yp[1] + yp[2] + yp[3];
    }
}

// ---------------------------------------------------------------- launcher
extern "C" void kernel_launch(void* const* d_in, const int* in_sizes, int n_in,
                              void* d_out, int out_size, void* d_ws, size_t ws_size,
                              hipStream_t stream) {
    (void)in_sizes; (void)n_in; (void)out_size; (void)ws_size;
    const float* H    = (const float*)d_in[0];
    const float* y0   = (const float*)d_in[1];
    const float* emb  = (const float*)d_in[2];
    const float* Wa   = (const float*)d_in[4];
    const float* Ua   = (const float*)d_in[5];
    const float* ba   = (const float*)d_in[6];
    const float* Va   = (const float*)d_in[7];
    const float* W    = (const float*)d_in[8];
    const float* U    = (const float*)d_in[9];
    const float* bias = (const float*)d_in[10];
    const float* Wy   = (const float*)d_in[11];
    const float* fcw  = (const float*)d_in[12];
    const float* fcb  = (const float*)d_in[13];

    float* out_y = (float*)d_out;              // (B, T)
    float* out_h = out_y + NB * NT;            // (B, T, HS)

    float* ws       = (float*)d_ws;
    float* c_st     = ws;                                   // B*HS
    float* y_st     = c_st + NB * NHS;                      // B
    float* y_part   = y_st + NB;                            // B*4
    float* cua_part = y_part + NB * 4;                      // B*4*128
    unsigned short* Hbf = (unsigned short*)(cua_part + NB * 4 * 128);  // BL*D
    unsigned short* Wab = Hbf + (size_t)BL * ND;            // T*N*D
    unsigned short* Ab0 = Wab + (size_t)NT * NN * ND;       // B*640
    unsigned short* Ab1 = Ab0 + (size_t)NB * NK;            // B*640
    unsigned short* Wg  = Ab1 + (size_t)NB * NK;            // T*2048*640

    hipLaunchKernelGGL(k_init, dim3((NB * NHS) / 256), dim3(256), 0, stream,
                       emb, y0, c_st, Ab0, y_st);
    hipLaunchKernelGGL(k_prep, dim3(BL * ND / (256 * 8)), dim3(256), 0, stream, H, Hbf);
    hipLaunchKernelGGL(k_prepwa, dim3(NT * NN), dim3(128), 0, stream, Wa, Wab);
    hipLaunchKernelGGL(k_prepw, dim3(32, 10, 24), dim3(256), 0, stream, W, U, Wg);
    hipLaunchKernelGGL(k_cua0, dim3(64, 4), dim3(256), 0, stream, c_st, Ua, cua_part);

    for (int t = 0; t < NT; ++t) {
        unsigned short* Ab  = (t & 1) ? Ab1 : Ab0;
        unsigned short* AbN = (t & 1) ? Ab0 : Ab1;
        hipLaunchKernelGGL(k_attn_fused, dim3(NB), dim3(384), 0, stream,
                           Hbf, Wab, Va, ba, cua_part, fcb, y_part, y_st, out_y, Ab, t);
        hipLaunchKernelGGL(k_gates_cell, dim3(64, 4), dim3(256), 0, stream,
                           Ab, AbN, Wg, bias, Wy, fcw, Ua, y_st, c_st,
                           out_h, y_part, cua_part, t);
    }
    hipLaunchKernelGGL(k_yfin, dim3(NB / 256), dim3(256), 0, stream, y_part, fcb, out_y);
}

// Round 5
// 1365.365 us; speedup vs baseline: 5.9532x; 1.1708x over previous
//
#include <hip/hip_runtime.h>
#include <math.h>

// Problem constants
constexpr int NB  = 1024;   // batch
constexpr int NL  = 96;     // seq len L
constexpr int ND  = 128;    // D
constexpr int NHS = 512;    // hidden
constexpr int NT  = 24;     // timesteps
constexpr int NN  = 128;    // attention dim N
constexpr int NG4 = 4 * NHS; // 2048
constexpr int NK  = ND + NHS; // 640 concat K
constexpr int BL  = NB * NL; // 98304

typedef __attribute__((ext_vector_type(8))) short bf16x8;
typedef __attribute__((ext_vector_type(4))) float f32x4;

static __device__ __forceinline__ unsigned short f2b(float x) {
    union { float f; unsigned u; } v; v.f = x;
    unsigned r = v.u + 0x7fffu + ((v.u >> 16) & 1u);   // RNE
    return (unsigned short)(r >> 16);
}
static __device__ __forceinline__ float b2f(unsigned short s) {
    union { unsigned u; float f; } v; v.u = ((unsigned)s) << 16;
    return v.f;
}

// fast transcendentals: exp2-based, inf-safe saturation, rel err ~1e-5 (bf16 noise floor)
constexpr float LOG2E  = 1.4426950408889634f;
static __device__ __forceinline__ float fast_exp(float x) {
    return __builtin_amdgcn_exp2f(x * LOG2E);
}
static __device__ __forceinline__ float fast_tanh(float x) {
    float e2 = __builtin_amdgcn_exp2f(x * (2.0f * LOG2E));   // e^{2x}
    return 1.0f - 2.0f * __builtin_amdgcn_rcpf(1.0f + e2);   // x>>0: e2=inf -> 1; x<<0: e2=0 -> -1
}
static __device__ __forceinline__ float fast_sigmoid(float x) {
    float e = __builtin_amdgcn_exp2f(-x * LOG2E);            // e^{-x}
    return __builtin_amdgcn_rcpf(1.0f + e);
}

// ---------------------------------------------------------------- init state
__global__ __launch_bounds__(256) void k_init(const float* __restrict__ emb,
                                              const float* __restrict__ y0,
                                              float* __restrict__ c,
                                              unsigned short* __restrict__ Ab0,
                                              float* __restrict__ y) {
    int idx = blockIdx.x * blockDim.x + threadIdx.x;
    if (idx < NB * NHS) {
        int b = idx / NHS, s = idx - b * NHS;
        Ab0[(size_t)b * NK + ND + s] = f2b(emb[b * 2 * NHS + s]);
        c[idx] = emb[b * 2 * NHS + NHS + s];
    }
    if (idx < NB) y[idx] = y0[idx];
}

// ---------------------------------------------------------------- H -> bf16
__global__ __launch_bounds__(256) void k_prep(const float* __restrict__ H,
                                              unsigned short* __restrict__ Hbf) {
    int idx = (blockIdx.x * 256 + threadIdx.x) * 8;
    float4 a = *(const float4*)(H + idx);
    float4 b = *(const float4*)(H + idx + 4);
    bf16x8 o;
    o[0] = (short)f2b(a.x); o[1] = (short)f2b(a.y);
    o[2] = (short)f2b(a.z); o[3] = (short)f2b(a.w);
    o[4] = (short)f2b(b.x); o[5] = (short)f2b(b.y);
    o[6] = (short)f2b(b.z); o[7] = (short)f2b(b.w);
    *(bf16x8*)(Hbf + idx) = o;
}

// ---------------------------------------------------------------- Wa -> bf16, [t][n][d] layout
__global__ __launch_bounds__(128) void k_prepwa(const float* __restrict__ Wa,
                                                unsigned short* __restrict__ Wab) {
    int tn = blockIdx.x;          // t*NN + n
    int t = tn / NN, n = tn - t * NN;
    int d = threadIdx.x;
    Wab[(size_t)tn * ND + d] = f2b(Wa[(size_t)d * (NT * NN) + t * NN + n]);
}

// ---------------------------------------------------------------- W,U -> bf16 Wg[t][kb][n][64]
// k-chunk-major layout: block (nc,kc,t) writes one contiguous 8 KB span.
__global__ __launch_bounds__(256) void k_prepw(const float* __restrict__ W,
                                               const float* __restrict__ U,
                                               unsigned short* __restrict__ Wg) {
    __shared__ unsigned short ts[64][66];
    int nc = blockIdx.x;    // 0..31
    int kc = blockIdx.y;    // 0..9  (= kb)
    int t  = blockIdx.z;    // 0..23
    int tid = threadIdx.x;
    int rowt = tid >> 4;         // 0..15
    int n4   = (tid & 15) << 2;  // 0..60 step 4
#pragma unroll
    for (int i = 0; i < 4; ++i) {
        int kl = i * 16 + rowt;
        int k  = kc * 64 + kl;
        const float* src = (k < ND) ? (W + (size_t)k * (NT * NG4))
                                    : (U + (size_t)(k - ND) * (NT * NG4));
        float4 v = *(const float4*)&src[t * NG4 + nc * 64 + n4];
        ts[kl][n4 + 0] = f2b(v.x);
        ts[kl][n4 + 1] = f2b(v.y);
        ts[kl][n4 + 2] = f2b(v.z);
        ts[kl][n4 + 3] = f2b(v.w);
    }
    __syncthreads();
    size_t base = (((size_t)t * 10 + kc) * NG4 + nc * 64) * 64;
#pragma unroll
    for (int p = 0; p < 2; ++p) {
        int flat = p * 256 + tid;
        int nl = flat >> 3, k8 = (flat & 7) << 3;
        bf16x8 o;
#pragma unroll
        for (int j = 0; j < 8; ++j) o[j] = (short)ts[k8 + j][nl];
        *(bf16x8*)&Wg[base + (size_t)nl * 64 + k8] = o;
    }
}

// ---------------------------------------------------------------- step-0 cua partials
__global__ __launch_bounds__(256) void k_cua0(const float* __restrict__ c,
                                              const float* __restrict__ Ua,
                                              float* __restrict__ cua_part) {
    __shared__ float cs[16][132];
    int m0 = blockIdx.x * 16, n0 = blockIdx.y;
    int tid = threadIdx.x;
#pragma unroll
    for (int i = 0; i < 8; ++i) {
        int idx = tid + i * 256;
        int row = idx >> 7, k = idx & 127;
        cs[row][k] = c[(size_t)(m0 + row) * NHS + n0 * 128 + k];
    }
    __syncthreads();
    int n = tid & 127, rg = tid >> 7;
    float a8[8] = {0, 0, 0, 0, 0, 0, 0, 0};
    for (int k = 0; k < 128; ++k) {
        float ua = Ua[(size_t)(n0 * 128 + k) * (NT * NN) + n];  // t = 0
#pragma unroll
        for (int i = 0; i < 8; ++i) a8[i] += cs[rg * 8 + i][k] * ua;
    }
#pragma unroll
    for (int i = 0; i < 8; ++i)
        cua_part[((size_t)(m0 + rg * 8 + i) * 4 + n0) * 128 + n] = a8[i];
}

// ---------------------------------------------------------------- fused attention (one block per b)
__global__ __launch_bounds__(384, 2) void k_attn_fused(
        const unsigned short* __restrict__ Hbf,
        const unsigned short* __restrict__ Wab,
        const float* __restrict__ Va,
        const float* __restrict__ ba,
        const float* __restrict__ cua_part,
        const float* __restrict__ fcb,
        const float* __restrict__ y_part,
        float* __restrict__ y_st,
        float* __restrict__ out_y,
        unsigned short* __restrict__ Ab,     // ping buffer for step t
        int t) {
    __shared__ unsigned short Ws[NN][136];   // 34.8 KB
    __shared__ float sc[NL];
    __shared__ float cua_s[NN];
    __shared__ float red[24][ND];            // 12.3 KB
    int tid = threadIdx.x;
    int b = blockIdx.x;

    // stage Wa[t] (n-major, d contiguous)
    const unsigned short* src = Wab + (size_t)t * NN * ND;
    for (int f = tid; f < 2048; f += 384) {
        int n = f >> 4, d0 = (f & 15) << 3;
        *(bf16x8*)&Ws[n][d0] = *(const bf16x8*)(src + n * ND + d0);
    }
    // sum cua partials (+ba fold)
    if (tid < 128) {
        const float* cp = cua_part + (size_t)b * 4 * 128 + tid;
        cua_s[tid] = cp[0] + cp[128] + cp[256] + cp[384] + ba[t * NN + tid];
    }
    // finalize y[t-1]
    if (t > 0 && tid == 383) {
        const float* yp = y_part + b * 4;
        float yv = fcb[t - 1] + yp[0] + yp[1] + yp[2] + yp[3];
        y_st[b] = yv;
        out_y[b * NT + (t - 1)] = yv;
    }
    __syncthreads();

    // MFMA scores: 6 waves, wave w -> rows 16w..16w+15 of this b
    int lane = tid & 63, wave = tid >> 6;
    int ln = lane & 15, kg = lane >> 4;
    const unsigned short* Hrow = Hbf + ((size_t)b * NL + wave * 16 + ln) * ND;

    f32x4 zero = {0.f, 0.f, 0.f, 0.f};
    f32x4 acc[8];
#pragma unroll
    for (int nt = 0; nt < 8; ++nt) acc[nt] = zero;
#pragma unroll
    for (int kc = 0; kc < 4; ++kc) {
        int d0 = kc * 32 + kg * 8;
        bf16x8 a = *(const bf16x8*)(Hrow + d0);
#pragma unroll
        for (int nt = 0; nt < 8; ++nt) {
            bf16x8 bb = *(const bf16x8*)&Ws[nt * 16 + ln][d0];
            acc[nt] = __builtin_amdgcn_mfma_f32_16x16x32_bf16(a, bb, acc[nt], 0, 0, 0);
        }
    }
    float va_l[8];
#pragma unroll
    for (int nt = 0; nt < 8; ++nt) va_l[nt] = Va[(nt * 16 + ln) * NT + t];
    const float scale = 0.044194173824159216f;  // 1/sqrt(512)
#pragma unroll
    for (int r = 0; r < 4; ++r) {
        float s = 0.f;
#pragma unroll
        for (int nt = 0; nt < 8; ++nt) {
            float pre = acc[nt][r] + cua_s[nt * 16 + ln];
            s += va_l[nt] * fast_tanh(pre);
        }
#pragma unroll
        for (int off = 1; off < 16; off <<= 1) s += __shfl_xor(s, off);
        if (ln == 0) sc[wave * 16 + kg * 4 + r] = s * scale;
    }
    __syncthreads();

    // softmax over 96 (wave 0)
    if (tid < 64) {
        float s0 = sc[tid];
        float s1 = (tid < 32) ? sc[64 + tid] : -1e30f;
        float m = fmaxf(s0, s1);
#pragma unroll
        for (int off = 32; off; off >>= 1) m = fmaxf(m, __shfl_xor(m, off));
        float p0 = fast_exp(s0 - m);
        float p1 = (tid < 32) ? fast_exp(s1 - m) : 0.f;
        float ssum = p0 + p1;
#pragma unroll
        for (int off = 32; off; off >>= 1) ssum += __shfl_xor(ssum, off);
        float inv = __builtin_amdgcn_rcpf(ssum);
        sc[tid] = p0 * inv;
        if (tid < 32) sc[64 + tid] = p1 * inv;
    }
    __syncthreads();

    // context: 24 l-groups x 16 d-chunks
    int dc = tid & 15, lg = tid >> 4;
    int d0 = dc * 8;
    const unsigned short* Hb = Hbf + (size_t)b * NL * ND;
    float a8[8] = {0, 0, 0, 0, 0, 0, 0, 0};
#pragma unroll
    for (int i = 0; i < 4; ++i) {
        int l = lg * 4 + i;
        bf16x8 hv = *(const bf16x8*)(Hb + l * ND + d0);
        float w = sc[l];
#pragma unroll
        for (int j = 0; j < 8; ++j) a8[j] += w * b2f((unsigned short)hv[j]);
    }
#pragma unroll
    for (int j = 0; j < 8; ++j) red[lg][d0 + j] = a8[j];
    __syncthreads();
    if (tid < ND) {
        float accd = 0.f;
#pragma unroll
        for (int g = 0; g < 24; ++g) accd += red[g][tid];
        Ab[(size_t)b * NK + tid] = f2b(accd);
    }
}

// ---------------------------------------------------------------- fused gates GEMM + cell update
// grid (64, 4): block = rows m0..m0+15, s-slice n0*128..+128 across all 4 gates.
__global__ __launch_bounds__(256, 2) void k_gates_cell(
        const unsigned short* __restrict__ Ab,   // read: [ht | h] for step t
        unsigned short* __restrict__ AbN,        // write: h for step t+1
        const unsigned short* __restrict__ Wg,   // [t][kb][n][64]
        const float* __restrict__ bias,
        const float* __restrict__ Wy,
        const float* __restrict__ fcw,
        const float* __restrict__ Ua,
        const float* __restrict__ y_st,
        float* __restrict__ c,
        float* __restrict__ out_h,
        float* __restrict__ y_part,
        float* __restrict__ cua_part,
        int t) {
    __shared__ __align__(16) char pool[73728];   // Bst[4][128][72] bf16 / epi arrays
    __shared__ float ys[16];
    __shared__ float yredL[16][2];
    int tid = threadIdx.x;
    int lane = tid & 63, wave = tid >> 6;
    int ln = lane & 15, kg = lane >> 4;
    int m0 = blockIdx.x * 16, n0 = blockIdx.y;

    if (tid < 16) ys[tid] = y_st[m0 + tid];

    unsigned short* BstW = (unsigned short*)pool + wave * (128 * 72);
    const unsigned short* Arow = Ab + (size_t)(m0 + ln) * NK;

    f32x4 zero = {0.f, 0.f, 0.f, 0.f};
    f32x4 acc[8];
#pragma unroll
    for (int nt = 0; nt < 8; ++nt) acc[nt] = zero;

    for (int kb = 0; kb < 10; ++kb) {           // K chunks of 64
        // contiguous 16 KB per-wave stage from [t][kb][n][64] layout
        const unsigned short* Wkb = Wg
            + (((size_t)(t * 10 + kb)) * NG4 + wave * NHS + n0 * 128) * 64;
#pragma unroll
        for (int i = 0; i < 16; ++i) {
            int flat = i * 64 + lane;
            int n = flat >> 3, k8 = (flat & 7) << 3;
            *(bf16x8*)&BstW[n * 72 + k8] = *(const bf16x8*)(Wkb + (size_t)n * 64 + k8);
        }
#pragma unroll
        for (int kc = 0; kc < 2; ++kc) {
            int d0 = kc * 32 + kg * 8;
            bf16x8 a = *(const bf16x8*)(Arow + kb * 64 + d0);
#pragma unroll
            for (int nt = 0; nt < 8; ++nt) {
                bf16x8 bb = *(const bf16x8*)&BstW[(nt * 16 + ln) * 72 + d0];
                acc[nt] = __builtin_amdgcn_mfma_f32_16x16x32_bf16(a, bb, acc[nt], 0, 0, 0);
            }
        }
    }
    __syncthreads();    // all waves done reading Bst before pool reuse

    float* gs = (float*)pool;                    // [4][16][132] = 33792 B
    float* cs = (float*)(pool + 33792);          // [16][132]
#pragma unroll
    for (int nt = 0; nt < 8; ++nt)
#pragma unroll
        for (int r = 0; r < 4; ++r)
            gs[wave * 2112 + (kg * 4 + r) * 132 + nt * 16 + ln] = acc[nt][r];
    __syncthreads();

    // cell update: thread -> s_loc, 8 rows
    int s_loc = tid & 127, rg = tid >> 7;
    int s_glob = n0 * 128 + s_loc;
    float prow[8];
#pragma unroll
    for (int i = 0; i < 8; ++i) {
        int row = rg * 8 + i;
        int b = m0 + row;
        float yp = ys[row];
        float gi = gs[0 * 2112 + row * 132 + s_loc] + bias[t * NG4 + s_glob]
                 + yp * Wy[t * NG4 + s_glob];
        float gf = gs[1 * 2112 + row * 132 + s_loc] + bias[t * NG4 + NHS + s_glob]
                 + yp * Wy[t * NG4 + NHS + s_glob];
        float gg = gs[2 * 2112 + row * 132 + s_loc] + bias[t * NG4 + 2 * NHS + s_glob]
                 + yp * Wy[t * NG4 + 2 * NHS + s_glob];
        float go = gs[3 * 2112 + row * 132 + s_loc] + bias[t * NG4 + 3 * NHS + s_glob]
                 + yp * Wy[t * NG4 + 3 * NHS + s_glob];
        float iv = fast_sigmoid(gi);
        float fv = fast_sigmoid(gf);
        float gv = fast_tanh(gg);
        float ov = fast_sigmoid(go);
        float cn = fv * c[(size_t)b * NHS + s_glob] + iv * gv;
        float hn = ov * fast_tanh(cn);
        c[(size_t)b * NHS + s_glob] = cn;
        cs[row * 132 + s_loc] = cn;
        AbN[(size_t)b * NK + ND + s_glob] = f2b(hn);
        out_h[(size_t)b * (NT * NHS) + t * NHS + s_glob] = hn;
        prow[i] = hn * fcw[t * NHS + s_glob];
    }
    // y partials
#pragma unroll
    for (int i = 0; i < 8; ++i) {
        float v = prow[i];
#pragma unroll
        for (int off = 32; off; off >>= 1) v += __shfl_xor(v, off);
        if (lane == 0) yredL[rg * 8 + i][(tid >> 6) & 1] = v;
    }
    __syncthreads();
    if (tid < 16)
        y_part[(size_t)(m0 + tid) * 4 + n0] = yredL[tid][0] + yredL[tid][1];

    // cua partial for step t+1 using fresh c (in cs)
    if (t + 1 < NT) {
        float a8[8] = {0, 0, 0, 0, 0, 0, 0, 0};
        int n = s_loc;
        for (int k = 0; k < 128; ++k) {
            float ua = Ua[(size_t)(n0 * 128 + k) * (NT * NN) + (t + 1) * NN + n];
#pragma unroll
            for (int i = 0; i < 8; ++i) a8[i] += cs[(rg * 8 + i) * 132 + k] * ua;
        }
#pragma unroll
        for (int i = 0; i < 8; ++i)
            cua_part[((size_t)(m0 + rg * 8 + i) * 4 + n0) * 128 + n] = a8[i];
    }
}

// ---------------------------------------------------------------- final y (t = NT-1)
__global__ __launch_bounds__(256) void k_yfin(const float* __restrict__ y_part,
                                              const float* __restrict__ fcb,
                                              float* __restrict__ out_y) {
    int b = blockIdx.x * 256 + threadIdx.x;
    if (b < NB) {
        const float* yp = y_part + (size_t)b * 4;
        out_y[b * NT + (NT - 1)] = fcb[NT - 1] + yp[0] + yp[1] + yp[2] + yp[3];
    }
}

// ---------------------------------------------------------------- launcher
extern "C" void kernel_launch(void* const* d_in, const int* in_sizes, int n_in,
                              void* d_out, int out_size, void* d_ws, size_t ws_size,
                              hipStream_t stream) {
    (void)in_sizes; (void)n_in; (void)out_size; (void)ws_size;
    const float* H    = (const float*)d_in[0];
    const float* y0   = (const float*)d_in[1];
    const float* emb  = (const float*)d_in[2];
    const float* Wa   = (const float*)d_in[4];
    const float* Ua   = (const float*)d_in[5];
    const float* ba   = (const float*)d_in[6];
    const float* Va   = (const float*)d_in[7];
    const float* W    = (const float*)d_in[8];
    const float* U    = (const float*)d_in[9];
    const float* bias = (const float*)d_in[10];
    const float* Wy   = (const float*)d_in[11];
    const float* fcw  = (const float*)d_in[12];
    const float* fcb  = (const float*)d_in[13];

    float* out_y = (float*)d_out;              // (B, T)
    float* out_h = out_y + NB * NT;            // (B, T, HS)

    float* ws       = (float*)d_ws;
    float* c_st     = ws;                                   // B*HS
    float* y_st     = c_st + NB * NHS;                      // B
    float* y_part   = y_st + NB;                            // B*4
    float* cua_part = y_part + NB * 4;                      // B*4*128
    unsigned short* Hbf = (unsigned short*)(cua_part + NB * 4 * 128);  // BL*D
    unsigned short* Wab = Hbf + (size_t)BL * ND;            // T*N*D
    unsigned short* Ab0 = Wab + (size_t)NT * NN * ND;       // B*640
    unsigned short* Ab1 = Ab0 + (size_t)NB * NK;            // B*640
    unsigned short* Wg  = Ab1 + (size_t)NB * NK;            // T*10*2048*64

    hipLaunchKernelGGL(k_init, dim3((NB * NHS) / 256), dim3(256), 0, stream,
                       emb, y0, c_st, Ab0, y_st);
    hipLaunchKernelGGL(k_prep, dim3(BL * ND / (256 * 8)), dim3(256), 0, stream, H, Hbf);
    hipLaunchKernelGGL(k_prepwa, dim3(NT * NN), dim3(128), 0, stream, Wa, Wab);
    hipLaunchKernelGGL(k_prepw, dim3(32, 10, 24), dim3(256), 0, stream, W, U, Wg);
    hipLaunchKernelGGL(k_cua0, dim3(64, 4), dim3(256), 0, stream, c_st, Ua, cua_part);

    for (int t = 0; t < NT; ++t) {
        unsigned short* Ab  = (t & 1) ? Ab1 : Ab0;
        unsigned short* AbN = (t & 1) ? Ab0 : Ab1;
        hipLaunchKernelGGL(k_attn_fused, dim3(NB), dim3(384), 0, stream,
                           Hbf, Wab, Va, ba, cua_part, fcb, y_part, y_st, out_y, Ab, t);
        hipLaunchKernelGGL(k_gates_cell, dim3(64, 4), dim3(256), 0, stream,
                           Ab, AbN, Wg, bias, Wy, fcw, Ua, y_st, c_st,
                           out_h, y_part, cua_part, t);
    }
    hipLaunchKernelGGL(k_yfin, dim3(NB / 256), dim3(256), 0, stream, y_part, fcb, out_y);
}